// Round 3
// baseline (330.614 us; speedup 1.0000x reference)
//
#include <hip/hip_runtime.h>
#include <cstdint>
#include <cstddef>

// ---------------------------------------------------------------------------
// FeedForwardQuantum: out = W2 @ relu(W1 @ (cos(theta)*cos(x[:,:8])) + b1) + b2
// M = 32768 tokens, K = 4096 (FFN), N = 1024 (EMBED).
// GEMM: 256x256 8-phase template (T2 swizzle + T3/T4 counted vmcnt + T5
// setprio), bf16 MFMA. H and W2 are produced pre-swizzled in global memory
// (granule ^= row&7 within each 64-elem K-block) so linear global_load_lds
// staging + XOR'd ds_read_b128 is bank-conflict-free (0 conflicts measured).
// Round 3: (a) M chunked at 16384 so the H-chunk is L3-resident during its
// GEMM (A-stage latency ~HBM -> ~L3); (b) all stages issued during tile u
// target tile u+2 (same buffer) with vmcnt(8) at tile end -> oldest
// outstanding DMA at the wait is ~7 phases old (covers full HBM latency).
// ---------------------------------------------------------------------------

#define M_TOT 32768L
#define N_DIM 1024
#define K_DIM 4096
#define BM 256
#define BN 256
#define BK 64
#define NT_K (K_DIM / BK)   // 64
#define CM_MAX 16384L

typedef __attribute__((ext_vector_type(8))) short short8;   // 8 x bf16
typedef __attribute__((ext_vector_type(4))) float f32x4;

__device__ __forceinline__ uint16_t f2bf(float f) {
  uint32_t u = __builtin_bit_cast(uint32_t, f);
  uint32_t r = (u + 0x7fffu + ((u >> 16) & 1u)) >> 16;   // RNE
  return (uint16_t)r;
}

__device__ __forceinline__ void gload_lds16(const void* gsrc, void* ldst) {
  __builtin_amdgcn_global_load_lds(
      (const __attribute__((address_space(1))) void*)gsrc,
      (__attribute__((address_space(3))) void*)ldst, 16, 0, 0);
}

// ---------------------------------------------------------------------------
// Kernel 1: W2 [1024][4096] fp32 -> bf16, swizzled:
//   elem (e,k) at e*4096 + (k & ~63) + (((k>>3)&7) ^ (e&7))*8 + (k&7)
// ---------------------------------------------------------------------------
__global__ __launch_bounds__(256) void prep_w2(const float* __restrict__ W2,
                                               uint16_t* __restrict__ W2sw) {
  long idx = (long)blockIdx.x * 256 + threadIdx.x;
  long e8 = idx * 8;
  int e = (int)(e8 >> 12);
  int k = (int)(e8 & 4095);
  float4 v0 = *(const float4*)(W2 + e8);
  float4 v1 = *(const float4*)(W2 + e8 + 4);
  union { uint16_t u[8]; uint4 v; } pk;
  pk.u[0] = f2bf(v0.x); pk.u[1] = f2bf(v0.y); pk.u[2] = f2bf(v0.z); pk.u[3] = f2bf(v0.w);
  pk.u[4] = f2bf(v1.x); pk.u[5] = f2bf(v1.y); pk.u[6] = f2bf(v1.z); pk.u[7] = f2bf(v1.w);
  int sg = ((k >> 3) & 7) ^ (e & 7);
  uint16_t* dst = W2sw + (long)e * 4096 + (k & ~63) + sg * 8;
  *(uint4*)dst = pk.v;
}

// ---------------------------------------------------------------------------
// Kernel 2: H[m][f] = relu(sum_i q[m][i]*W1[f][i] + b1[f]),  bf16, swizzled.
// ---------------------------------------------------------------------------
__global__ __launch_bounds__(256) void h_kernel(const float* __restrict__ x,
                                                const float* __restrict__ theta,
                                                const float* __restrict__ W1,
                                                const float* __restrict__ b1,
                                                uint16_t* __restrict__ Hsw) {
  __shared__ float qs[64][8];
  int tid = threadIdx.x;
  long m0 = (long)blockIdx.x * 64;
  int f = blockIdx.y * 256 + tid;

  for (int idx = tid; idx < 512; idx += 256) {
    int t = idx >> 3, i = idx & 7;
    qs[t][i] = __cosf(theta[i]) * cosf(x[(m0 + t) * 1024 + i]);
  }
  __syncthreads();

  const float4* w1p = (const float4*)(W1 + (long)f * 8);
  float4 wa = w1p[0];
  float4 wb = w1p[1];
  float bb = b1[f];
  int fblk = f & ~63;
  int grp = (f >> 3) & 7;
  int fw = f & 7;

#pragma unroll 4
  for (int t = 0; t < 64; ++t) {
    long m = m0 + t;
    const float* q = qs[t];
    float h = bb;
    h += q[0] * wa.x + q[1] * wa.y + q[2] * wa.z + q[3] * wa.w;
    h += q[4] * wb.x + q[5] * wb.y + q[6] * wb.z + q[7] * wb.w;
    h = fmaxf(h, 0.0f);
    int sg = grp ^ ((int)m & 7);
    Hsw[m * K_DIM + fblk + sg * 8 + fw] = f2bf(h);
  }
}

// ---------------------------------------------------------------------------
// Kernel 3: 256x256 8-phase GEMM.  out[m][n] = sum_k H[m][k]*W2[n][k] + b2[n]
// 8 waves (2M x 4N), each owns 128x64 output = acc[8][4] f32x4.
// LDS: A,B double-buffered [2][256][64] bf16 = 128 KiB total.
// Staging schedule (all targets tile u+2, same buffer p as tile u; each
// region staged >=1 phase after its last ds_read):
//   A j0 (rows 0-63/128-191): read P0  -> staged P1
//   B rows: read P0+P1        -> Bh0 staged P2, Bh1 staged P3
//   A j1 (rows 64-127/192-255): read P2 -> staged P3
// vmcnt(8) at tile end keeps tile u+2's 8 calls in flight; everything for
// tile u+1 (issued during u-1, 4-7 phases earlier) is guaranteed landed.
// ---------------------------------------------------------------------------
__global__ __launch_bounds__(512, 2) void gemm_kernel(const uint16_t* __restrict__ Hsw,
                                                      const uint16_t* __restrict__ W2sw,
                                                      const float* __restrict__ b2,
                                                      float* __restrict__ out) {
  __shared__ uint16_t LA[2 * BM * BK];   // 64 KiB
  __shared__ uint16_t LB[2 * BN * BK];   // 64 KiB

  int nwg = gridDim.x;
  int bid = blockIdx.x;
  int sw = bid;
  if ((nwg & 7) == 0) { int cpx = nwg >> 3; sw = (bid & 7) * cpx + (bid >> 3); }
  const int NTN = N_DIM / BN;            // 4
  int mt = sw / NTN;
  int nt = sw - mt * NTN;
  long m0 = (long)mt * BM;
  int n0 = nt * BN;

  int tid = threadIdx.x;
  int lane = tid & 63;
  int wave_m = (tid >> 6) >> 2;          // 0..1
  int wave_n = (tid >> 6) & 3;           // 0..3
  int wmB = wave_m * 128;
  int wnB = wave_n * 64;

  int r  = lane & 15;
  int kq = lane >> 4;
  int xr = r & 7;

  // staging addresses: thread covers row (tid>>3) of each 64-row region,
  // 16B at col granule (tid&7). Source is pre-swizzled -> pure linear copy.
  int rowS = tid >> 3;
  int colS = (tid & 7) * 8;
  const uint16_t* srcA = Hsw  + (m0 + rowS) * K_DIM + colS;
  const uint16_t* srcB = W2sw + ((long)(n0 + rowS)) * K_DIM + colS;
  int ldsWB = (tid & ~63) * 8;           // wave-uniform elem offset in region

#define STAGE_A(p, h, j, t) \
  gload_lds16(srcA + (long)((h)*128 + (j)*64) * K_DIM + (t)*BK, \
              &LA[(p)*16384 + ((h)*128 + (j)*64)*BK + ldsWB])
#define STAGE_B(p, h, j, t) \
  gload_lds16(srcB + (long)((h)*128 + (j)*64) * K_DIM + (t)*BK, \
              &LB[(p)*16384 + ((h)*128 + (j)*64)*BK + ldsWB])

#define BAR() do { asm volatile("" ::: "memory"); __builtin_amdgcn_s_barrier(); \
                   asm volatile("" ::: "memory"); } while (0)

#define LDA_F(p, mf_, ks_) \
  (*(const short8*)&LA[(p)*16384 + (wmB + (mf_)*16 + r)*BK + ((((ks_)*4 + kq) ^ xr)*8)])
#define LDB_F(p, nf_, ks_) \
  (*(const short8*)&LB[(p)*16384 + (wnB + (nf_)*16 + r)*BK + ((((ks_)*4 + kq) ^ xr)*8)])

#define MFMA_PHASE(mh, nh) do { \
    __builtin_amdgcn_s_setprio(1); \
    _Pragma("unroll") for (int i_ = 0; i_ < 4; ++i_) \
    _Pragma("unroll") for (int j_ = 0; j_ < 2; ++j_) \
    _Pragma("unroll") for (int ks_ = 0; ks_ < 2; ++ks_) \
      acc[(mh)*4 + i_][(nh)*2 + j_] = __builtin_amdgcn_mfma_f32_16x16x32_bf16( \
          a[i_][ks_], bq[(nh)][j_][ks_], acc[(mh)*4 + i_][(nh)*2 + j_], 0, 0, 0); \
    __builtin_amdgcn_s_setprio(0); \
  } while (0)

  f32x4 acc[8][4];
#pragma unroll
  for (int i = 0; i < 8; ++i)
#pragma unroll
    for (int j = 0; j < 4; ++j) acc[i][j] = (f32x4){0.f, 0.f, 0.f, 0.f};

  short8 a[4][2];        // current mh quadrant A frags
  short8 bq[2][2][2];    // [nh][nf2][ks] B frags, both sets live

  // ---- prologue: tile0 -> buf0 (8 calls), tile1 -> buf1 (8 calls)
#pragma unroll
  for (int h = 0; h < 2; ++h)
#pragma unroll
    for (int j = 0; j < 2; ++j) STAGE_A(0, h, j, 0);
#pragma unroll
  for (int h = 0; h < 2; ++h)
#pragma unroll
    for (int j = 0; j < 2; ++j) STAGE_B(0, h, j, 0);
#pragma unroll
  for (int h = 0; h < 2; ++h)
#pragma unroll
    for (int j = 0; j < 2; ++j) STAGE_A(1, h, j, 1);
#pragma unroll
  for (int h = 0; h < 2; ++h)
#pragma unroll
    for (int j = 0; j < 2; ++j) STAGE_B(1, h, j, 1);
  asm volatile("s_waitcnt vmcnt(8)" ::: "memory");   // tile0 fully landed
  BAR();

#pragma unroll 2
  for (int u = 0; u < NT_K; ++u) {
    int p = u & 1;
    bool st = (u < NT_K - 2);
    // ---- P0: read A[mh=0] (8) + B[nh=0] (4)
#pragma unroll
    for (int i = 0; i < 4; ++i)
#pragma unroll
      for (int ks = 0; ks < 2; ++ks) a[i][ks] = LDA_F(p, i, ks);
#pragma unroll
    for (int j = 0; j < 2; ++j)
#pragma unroll
      for (int ks = 0; ks < 2; ++ks) bq[0][j][ks] = LDB_F(p, j, ks);
    BAR();
    MFMA_PHASE(0, 0);
    BAR();
    // ---- P1: read B[nh=1] (4); stage A j0 of u+2 (rows fully read @P0)
#pragma unroll
    for (int j = 0; j < 2; ++j)
#pragma unroll
      for (int ks = 0; ks < 2; ++ks) bq[1][j][ks] = LDB_F(p, 2 + j, ks);
    if (st) { STAGE_A(p, 0, 0, u + 2); STAGE_A(p, 1, 0, u + 2); }
    BAR();
    MFMA_PHASE(0, 1);
    BAR();
    // ---- P2: read A[mh=1] (8); stage B half0 of u+2 (rows read @P0/P1)
#pragma unroll
    for (int i = 0; i < 4; ++i)
#pragma unroll
      for (int ks = 0; ks < 2; ++ks) a[i][ks] = LDA_F(p, 4 + i, ks);
    if (st) { STAGE_B(p, 0, 0, u + 2); STAGE_B(p, 0, 1, u + 2); }
    BAR();
    MFMA_PHASE(1, 1);
    BAR();
    // ---- P3: stage A j1 (rows read @P2) + B half1 of u+2; counted vmcnt
    if (st) { STAGE_A(p, 0, 1, u + 2); STAGE_A(p, 1, 1, u + 2);
              STAGE_B(p, 1, 0, u + 2); STAGE_B(p, 1, 1, u + 2); }
    BAR();
    MFMA_PHASE(1, 0);
    if (st) { asm volatile("s_waitcnt vmcnt(8)" ::: "memory"); }
    else    { asm volatile("s_waitcnt vmcnt(0)" ::: "memory"); }
    BAR();
  }

  // ---- epilogue: C/D layout col = lane&15 (n), row = kq*4 + reg (m)
  float bb[4];
#pragma unroll
  for (int nf = 0; nf < 4; ++nf) bb[nf] = b2[n0 + wnB + nf * 16 + r];
  long mbase = m0 + wmB + kq * 4;
#pragma unroll
  for (int mf = 0; mf < 8; ++mf) {
#pragma unroll
    for (int nf = 0; nf < 4; ++nf) {
      int n = n0 + wnB + nf * 16 + r;
#pragma unroll
      for (int rg = 0; rg < 4; ++rg) {
        out[(mbase + mf * 16 + rg) * N_DIM + n] = acc[mf][nf][rg] + bb[nf];
      }
    }
  }
#undef STAGE_A
#undef STAGE_B
#undef BAR
#undef LDA_F
#undef LDB_F
#undef MFMA_PHASE
}

// ---------------------------------------------------------------------------
extern "C" void kernel_launch(void* const* d_in, const int* in_sizes, int n_in,
                              void* d_out, int out_size, void* d_ws, size_t ws_size,
                              hipStream_t stream) {
  const float* x     = (const float*)d_in[0];
  const float* theta = (const float*)d_in[1];
  const float* W1    = (const float*)d_in[2];
  const float* b1    = (const float*)d_in[3];
  const float* W2    = (const float*)d_in[4];
  const float* b2    = (const float*)d_in[5];
  float* out = (float*)d_out;

  const size_t W2SW_BYTES = (size_t)N_DIM * K_DIM * 2;   // 8 MiB
  uint16_t* W2sw = (uint16_t*)d_ws;
  uint16_t* Hsw  = (uint16_t*)((char*)d_ws + W2SW_BYTES);

  size_t avail = ws_size > W2SW_BYTES ? ws_size - W2SW_BYTES : 0;
  long CM = (long)(avail / ((size_t)K_DIM * 2));
  CM &= ~255L;                       // multiple of BM=256
  if (CM > CM_MAX) CM = CM_MAX;      // keep H-chunk (134 MB) L3-resident
  if (CM < 256) CM = 256;

  prep_w2<<<2048, 256, 0, stream>>>(W2, W2sw);

  for (long m0 = 0; m0 < M_TOT; m0 += CM) {
    long mc = M_TOT - m0;
    if (mc > CM) mc = CM;
    dim3 gA((unsigned)(mc / 64), K_DIM / 256);
    h_kernel<<<gA, 256, 0, stream>>>(x + m0 * N_DIM, theta, W1, b1, Hsw);
    unsigned ngb = (unsigned)((mc / BM) * (N_DIM / BN));
    gemm_kernel<<<ngb, 512, 0, stream>>>(Hsw, W2sw, b2, out + m0 * N_DIM);
  }
}

// Round 4
// 313.671 us; speedup vs baseline: 1.0540x; 1.0540x over previous
//
#include <hip/hip_runtime.h>
#include <cstdint>
#include <cstddef>

// ---------------------------------------------------------------------------
// FeedForwardQuantum: out = W2 @ relu(W1 @ (cos(theta)*cos(x[:,:8])) + b1) + b2
// M = 32768, K = 4096 (FFN), N = 1024 (EMBED).
// Round 4: rotated-region GEMM schedule. Each region = {MFMA; ds_reads for
// next region; stages; BAR} (one barrier/phase, 4/tile) so the LDS pipe works
// WHILE the MFMA pipe drains, instead of the old reads->BAR->MFMA->BAR
// lockstep that serialized them (45% MfmaUtil ceiling = 2484cy MFMA + 1536cy
// LDS reads fully serial).
// Safety invariants (hand-verified):
//  - WAR (DMA overwrites LDS region R): stage of R issued >= 2 barriers after
//    R's last ds_read-issue; reads drain per-wave at their lgkm wait (before
//    the next MFMA), block-wide by the following barrier.
//  - RAW (read R before DMA landed): tile u+1's 8 DMAs are the 8 oldest at
//    vmcnt(4)@P3(u); reads of u+1 happen after BAR(P3 end), so every wave
//    passed its own vmcnt(4) -> block-wide landed.
//  - Register WAR (reads overwrite frags the just-issued MFMA consumes):
//    in-order issue => MFMA reads operands before the later ds_read returns.
// ---------------------------------------------------------------------------

#define M_TOT 32768L
#define N_DIM 1024
#define K_DIM 4096
#define BM 256
#define BN 256
#define BK 64
#define NT_K (K_DIM / BK)   // 64
#define CM_MAX 16384L

typedef __attribute__((ext_vector_type(8))) short short8;   // 8 x bf16
typedef __attribute__((ext_vector_type(4))) float f32x4;

__device__ __forceinline__ uint16_t f2bf(float f) {
  uint32_t u = __builtin_bit_cast(uint32_t, f);
  uint32_t r = (u + 0x7fffu + ((u >> 16) & 1u)) >> 16;   // RNE
  return (uint16_t)r;
}

__device__ __forceinline__ void gload_lds16(const void* gsrc, void* ldst) {
  __builtin_amdgcn_global_load_lds(
      (const __attribute__((address_space(1))) void*)gsrc,
      (__attribute__((address_space(3))) void*)ldst, 16, 0, 0);
}

// ---------------------------------------------------------------------------
// Kernel 1: W2 [1024][4096] fp32 -> bf16, swizzled:
//   elem (e,k) at e*4096 + (k & ~63) + (((k>>3)&7) ^ (e&7))*8 + (k&7)
// ---------------------------------------------------------------------------
__global__ __launch_bounds__(256) void prep_w2(const float* __restrict__ W2,
                                               uint16_t* __restrict__ W2sw) {
  long idx = (long)blockIdx.x * 256 + threadIdx.x;
  long e8 = idx * 8;
  int e = (int)(e8 >> 12);
  int k = (int)(e8 & 4095);
  float4 v0 = *(const float4*)(W2 + e8);
  float4 v1 = *(const float4*)(W2 + e8 + 4);
  union { uint16_t u[8]; uint4 v; } pk;
  pk.u[0] = f2bf(v0.x); pk.u[1] = f2bf(v0.y); pk.u[2] = f2bf(v0.z); pk.u[3] = f2bf(v0.w);
  pk.u[4] = f2bf(v1.x); pk.u[5] = f2bf(v1.y); pk.u[6] = f2bf(v1.z); pk.u[7] = f2bf(v1.w);
  int sg = ((k >> 3) & 7) ^ (e & 7);
  uint16_t* dst = W2sw + (long)e * 4096 + (k & ~63) + sg * 8;
  *(uint4*)dst = pk.v;
}

// ---------------------------------------------------------------------------
// Kernel 2: H[m][f] = relu(sum_i q[m][i]*W1[f][i] + b1[f]),  bf16, swizzled.
// ---------------------------------------------------------------------------
__global__ __launch_bounds__(256) void h_kernel(const float* __restrict__ x,
                                                const float* __restrict__ theta,
                                                const float* __restrict__ W1,
                                                const float* __restrict__ b1,
                                                uint16_t* __restrict__ Hsw) {
  __shared__ float qs[64][8];
  int tid = threadIdx.x;
  long m0 = (long)blockIdx.x * 64;
  int f = blockIdx.y * 256 + tid;

  for (int idx = tid; idx < 512; idx += 256) {
    int t = idx >> 3, i = idx & 7;
    qs[t][i] = __cosf(theta[i]) * cosf(x[(m0 + t) * 1024 + i]);
  }
  __syncthreads();

  const float4* w1p = (const float4*)(W1 + (long)f * 8);
  float4 wa = w1p[0];
  float4 wb = w1p[1];
  float bb = b1[f];
  int fblk = f & ~63;
  int grp = (f >> 3) & 7;
  int fw = f & 7;

#pragma unroll 4
  for (int t = 0; t < 64; ++t) {
    long m = m0 + t;
    const float* q = qs[t];
    float h = bb;
    h += q[0] * wa.x + q[1] * wa.y + q[2] * wa.z + q[3] * wa.w;
    h += q[4] * wb.x + q[5] * wb.y + q[6] * wb.z + q[7] * wb.w;
    h = fmaxf(h, 0.0f);
    int sg = grp ^ ((int)m & 7);
    Hsw[m * K_DIM + fblk + sg * 8 + fw] = f2bf(h);
  }
}

// ---------------------------------------------------------------------------
// Kernel 3: 256x256 rotated-region GEMM. out[m][n] = sum_k H[m][k]*W2[n][k]+b2
// 8 waves (2M x 4N), wave tile 128x64, acc[8][4] f32x4.
// LDS: A,B double-buffered [2][256][64] bf16 = 128 KiB.
// Per K-tile u (buffer p = u&1), 4 regions, each ends in ONE barrier:
//  P0: reads a<-A[mh0],bq0<-B[nh0] (12); MFMA(0,0); reads bq1<-B[nh1] (4)
//  P1: MFMA(0,1); reads a<-A[mh1] (8);  stage A-j0 (u+2)
//  P2: MFMA(1,1);                        stage B-h0 (u+2)
//  P3: MFMA(1,0); vmcnt(4|0);            stage A-j1 + B-h1 (u+2)
// ---------------------------------------------------------------------------
__global__ __launch_bounds__(512, 2) void gemm_kernel(const uint16_t* __restrict__ Hsw,
                                                      const uint16_t* __restrict__ W2sw,
                                                      const float* __restrict__ b2,
                                                      float* __restrict__ out) {
  __shared__ uint16_t LA[2 * BM * BK];   // 64 KiB
  __shared__ uint16_t LB[2 * BN * BK];   // 64 KiB

  int nwg = gridDim.x;
  int bid = blockIdx.x;
  int sw = bid;
  if ((nwg & 7) == 0) { int cpx = nwg >> 3; sw = (bid & 7) * cpx + (bid >> 3); }
  const int NTN = N_DIM / BN;            // 4
  int mt = sw / NTN;
  int nt = sw - mt * NTN;
  long m0 = (long)mt * BM;
  int n0 = nt * BN;

  int tid = threadIdx.x;
  int lane = tid & 63;
  int wave_m = (tid >> 6) >> 2;          // 0..1
  int wave_n = (tid >> 6) & 3;           // 0..3
  int wmB = wave_m * 128;
  int wnB = wave_n * 64;

  int r  = lane & 15;
  int kq = lane >> 4;
  int xr = r & 7;

  int rowS = tid >> 3;
  int colS = (tid & 7) * 8;
  const uint16_t* srcA = Hsw  + (m0 + rowS) * K_DIM + colS;
  const uint16_t* srcB = W2sw + ((long)(n0 + rowS)) * K_DIM + colS;
  int ldsWB = (tid & ~63) * 8;

#define STAGE_A(p, h, j, t) \
  gload_lds16(srcA + (long)((h)*128 + (j)*64) * K_DIM + (t)*BK, \
              &LA[(p)*16384 + ((h)*128 + (j)*64)*BK + ldsWB])
#define STAGE_B(p, h, j, t) \
  gload_lds16(srcB + (long)((h)*128 + (j)*64) * K_DIM + (t)*BK, \
              &LB[(p)*16384 + ((h)*128 + (j)*64)*BK + ldsWB])

#define BAR() do { asm volatile("" ::: "memory"); __builtin_amdgcn_s_barrier(); \
                   asm volatile("" ::: "memory"); } while (0)

#define LDA_F(p, mf_, ks_) \
  (*(const short8*)&LA[(p)*16384 + (wmB + (mf_)*16 + r)*BK + ((((ks_)*4 + kq) ^ xr)*8)])
#define LDB_F(p, nf_, ks_) \
  (*(const short8*)&LB[(p)*16384 + (wnB + (nf_)*16 + r)*BK + ((((ks_)*4 + kq) ^ xr)*8)])

#define MFMA_PHASE(mh, nh) do { \
    __builtin_amdgcn_s_setprio(1); \
    _Pragma("unroll") for (int i_ = 0; i_ < 4; ++i_) \
    _Pragma("unroll") for (int j_ = 0; j_ < 2; ++j_) \
    _Pragma("unroll") for (int ks_ = 0; ks_ < 2; ++ks_) \
      acc[(mh)*4 + i_][(nh)*2 + j_] = __builtin_amdgcn_mfma_f32_16x16x32_bf16( \
          a[i_][ks_], bq[(nh)][j_][ks_], acc[(mh)*4 + i_][(nh)*2 + j_], 0, 0, 0); \
    __builtin_amdgcn_s_setprio(0); \
  } while (0)

  f32x4 acc[8][4];
#pragma unroll
  for (int i = 0; i < 8; ++i)
#pragma unroll
    for (int j = 0; j < 4; ++j) acc[i][j] = (f32x4){0.f, 0.f, 0.f, 0.f};

  short8 a[4][2];        // current mh-half A frags (reused mh0 -> mh1 -> next tile)
  short8 bq[2][2][2];    // [nh][nf2][ks] B frags for current tile

  // ---- prologue: tile0 -> buf0 (8 calls), tile1 -> buf1 (8 calls)
#pragma unroll
  for (int h = 0; h < 2; ++h)
#pragma unroll
    for (int j = 0; j < 2; ++j) STAGE_A(0, h, j, 0);
#pragma unroll
  for (int h = 0; h < 2; ++h)
#pragma unroll
    for (int j = 0; j < 2; ++j) STAGE_B(0, h, j, 0);
#pragma unroll
  for (int h = 0; h < 2; ++h)
#pragma unroll
    for (int j = 0; j < 2; ++j) STAGE_A(1, h, j, 1);
#pragma unroll
  for (int h = 0; h < 2; ++h)
#pragma unroll
    for (int j = 0; j < 2; ++j) STAGE_B(1, h, j, 1);
  asm volatile("s_waitcnt vmcnt(8)" ::: "memory");   // own tile-0 DMAs landed
  BAR();                                             // -> block-wide landed

#pragma unroll 2
  for (int u = 0; u < NT_K; ++u) {
    int p = u & 1;
    bool st = (u < NT_K - 2);

    // ---- P0: tile-boundary reads (after the barrier => RAW-safe), MFMA(0,0),
    //          then pipelined bq1 reads that overlap MFMA(0,0)'s drain.
#pragma unroll
    for (int i = 0; i < 4; ++i)
#pragma unroll
      for (int ks = 0; ks < 2; ++ks) a[i][ks] = LDA_F(p, i, ks);
#pragma unroll
    for (int j = 0; j < 2; ++j)
#pragma unroll
      for (int ks = 0; ks < 2; ++ks) bq[0][j][ks] = LDB_F(p, j, ks);
    MFMA_PHASE(0, 0);
#pragma unroll
    for (int j = 0; j < 2; ++j)
#pragma unroll
      for (int ks = 0; ks < 2; ++ks) bq[1][j][ks] = LDB_F(p, 2 + j, ks);
    BAR();

    // ---- P1: MFMA(0,1) overlaps a<-A[mh1] reads; stage A-j0 of u+2.
    MFMA_PHASE(0, 1);
#pragma unroll
    for (int i = 0; i < 4; ++i)
#pragma unroll
      for (int ks = 0; ks < 2; ++ks) a[i][ks] = LDA_F(p, 4 + i, ks);
    if (st) { STAGE_A(p, 0, 0, u + 2); STAGE_A(p, 1, 0, u + 2); }
    BAR();

    // ---- P2: MFMA(1,1); stage B-h0 of u+2.
    MFMA_PHASE(1, 1);
    if (st) { STAGE_B(p, 0, 0, u + 2); STAGE_B(p, 0, 1, u + 2); }
    BAR();

    // ---- P3: MFMA(1,0); counted vmcnt (drains tile u+1's 8 oldest DMAs);
    //          stage A-j1 + B-h1 of u+2.
    MFMA_PHASE(1, 0);
    if (st)                 { asm volatile("s_waitcnt vmcnt(4)" ::: "memory"); }
    else if (u == NT_K - 2) { asm volatile("s_waitcnt vmcnt(0)" ::: "memory"); }
    if (st) { STAGE_A(p, 0, 1, u + 2); STAGE_A(p, 1, 1, u + 2);
              STAGE_B(p, 1, 0, u + 2); STAGE_B(p, 1, 1, u + 2); }
    BAR();
  }

  // ---- epilogue: C/D layout col = lane&15 (n), row = kq*4 + reg (m)
  float bb[4];
#pragma unroll
  for (int nf = 0; nf < 4; ++nf) bb[nf] = b2[n0 + wnB + nf * 16 + r];
  long mbase = m0 + wmB + kq * 4;
#pragma unroll
  for (int mf = 0; mf < 8; ++mf) {
#pragma unroll
    for (int nf = 0; nf < 4; ++nf) {
      int n = n0 + wnB + nf * 16 + r;
#pragma unroll
      for (int rg = 0; rg < 4; ++rg) {
        out[(mbase + mf * 16 + rg) * N_DIM + n] = acc[mf][nf][rg] + bb[nf];
      }
    }
  }
#undef STAGE_A
#undef STAGE_B
#undef BAR
#undef LDA_F
#undef LDB_F
#undef MFMA_PHASE
}

// ---------------------------------------------------------------------------
extern "C" void kernel_launch(void* const* d_in, const int* in_sizes, int n_in,
                              void* d_out, int out_size, void* d_ws, size_t ws_size,
                              hipStream_t stream) {
  const float* x     = (const float*)d_in[0];
  const float* theta = (const float*)d_in[1];
  const float* W1    = (const float*)d_in[2];
  const float* b1    = (const float*)d_in[3];
  const float* W2    = (const float*)d_in[4];
  const float* b2    = (const float*)d_in[5];
  float* out = (float*)d_out;

  const size_t W2SW_BYTES = (size_t)N_DIM * K_DIM * 2;   // 8 MiB
  uint16_t* W2sw = (uint16_t*)d_ws;
  uint16_t* Hsw  = (uint16_t*)((char*)d_ws + W2SW_BYTES);

  size_t avail = ws_size > W2SW_BYTES ? ws_size - W2SW_BYTES : 0;
  long CM = (long)(avail / ((size_t)K_DIM * 2));
  CM &= ~255L;                       // multiple of BM=256
  if (CM > CM_MAX) CM = CM_MAX;      // keep H-chunk (134 MB) L3-resident
  if (CM < 256) CM = 256;

  prep_w2<<<2048, 256, 0, stream>>>(W2, W2sw);

  for (long m0 = 0; m0 < M_TOT; m0 += CM) {
    long mc = M_TOT - m0;
    if (mc > CM) mc = CM;
    dim3 gA((unsigned)(mc / 64), K_DIM / 256);
    h_kernel<<<gA, 256, 0, stream>>>(x + m0 * N_DIM, theta, W1, b1, Hsw);
    unsigned ngb = (unsigned)((mc / BM) * (N_DIM / BN));
    gemm_kernel<<<ngb, 512, 0, stream>>>(Hsw, W2sw, b2, out + m0 * N_DIM);
  }
}

// Round 5
// 308.990 us; speedup vs baseline: 1.0700x; 1.0152x over previous
//
#include <hip/hip_runtime.h>
#include <cstdint>
#include <cstddef>

// ---------------------------------------------------------------------------
// FeedForwardQuantum: out = W2 @ relu(W1 @ (cos(theta)*cos(x[:,:8])) + b1) + b2
// M = 32768, K = 4096 (FFN), N = 1024 (EMBED).
// Round 5: fully-rotated GEMM schedule — every MFMA phase consumes fragments
// read >=1 phase earlier, so no MFMA ever sits behind a fresh 12-read batch.
//  P0: MFMA(0,0)[a0,b0];  read b1v(4)+a1(8)        (slack: P1/P2)   ; BAR
//  P1: MFMA(0,1)[a0,b1v]; stage A-j0(u+2)                           ; BAR
//  P2: MFMA(1,1)[a1,b1v]; stage B-all(u+2); vmcnt(6)                ; BAR
//  P3: MFMA(1,0)[a1,b0];  read a0,b0 of tile u+1 (buffer p^1);
//      stage A-j1(u+2)                                              ; BAR
// vmcnt(6)@P2: outstanding = 8 (tile u+1, oldest) + 6 (tile u's stages) ->
// drains exactly u+1; BAR makes it block-wide => P3's p^1 reads are RAW-safe.
// Region WAR (stage >= 1 barrier after last consuming MFMA, all waves):
//  A-j0 consumed @P0 -> staged P1 | B consumed @P0/P1 -> staged P2 |
//  A-j1 consumed @P2 -> staged P3.
// ---------------------------------------------------------------------------

#define M_TOT 32768L
#define N_DIM 1024
#define K_DIM 4096
#define BM 256
#define BN 256
#define BK 64
#define NT_K (K_DIM / BK)   // 64
#define CM_MAX 16384L

typedef __attribute__((ext_vector_type(8))) short short8;   // 8 x bf16
typedef __attribute__((ext_vector_type(4))) float f32x4;

__device__ __forceinline__ uint16_t f2bf(float f) {
  uint32_t u = __builtin_bit_cast(uint32_t, f);
  uint32_t r = (u + 0x7fffu + ((u >> 16) & 1u)) >> 16;   // RNE
  return (uint16_t)r;
}

__device__ __forceinline__ void gload_lds16(const void* gsrc, void* ldst) {
  __builtin_amdgcn_global_load_lds(
      (const __attribute__((address_space(1))) void*)gsrc,
      (__attribute__((address_space(3))) void*)ldst, 16, 0, 0);
}

// ---------------------------------------------------------------------------
// Kernel 1: W2 [1024][4096] fp32 -> bf16, swizzled:
//   elem (e,k) at e*4096 + (k & ~63) + (((k>>3)&7) ^ (e&7))*8 + (k&7)
// ---------------------------------------------------------------------------
__global__ __launch_bounds__(256) void prep_w2(const float* __restrict__ W2,
                                               uint16_t* __restrict__ W2sw) {
  long idx = (long)blockIdx.x * 256 + threadIdx.x;
  long e8 = idx * 8;
  int e = (int)(e8 >> 12);
  int k = (int)(e8 & 4095);
  float4 v0 = *(const float4*)(W2 + e8);
  float4 v1 = *(const float4*)(W2 + e8 + 4);
  union { uint16_t u[8]; uint4 v; } pk;
  pk.u[0] = f2bf(v0.x); pk.u[1] = f2bf(v0.y); pk.u[2] = f2bf(v0.z); pk.u[3] = f2bf(v0.w);
  pk.u[4] = f2bf(v1.x); pk.u[5] = f2bf(v1.y); pk.u[6] = f2bf(v1.z); pk.u[7] = f2bf(v1.w);
  int sg = ((k >> 3) & 7) ^ (e & 7);
  uint16_t* dst = W2sw + (long)e * 4096 + (k & ~63) + sg * 8;
  *(uint4*)dst = pk.v;
}

// ---------------------------------------------------------------------------
// Kernel 2 (v2): H[m][f] = relu(sum_i q[m][i]*W1[f][i] + b1[f]), bf16,
// swizzled. Thread owns one 8-wide f-granule g for 64 rows -> one uint4
// (b128) store per row (8x fewer store instrs than per-f scalar stores).
// grid = (mc/64, 512/256 = 2), block 256.
// ---------------------------------------------------------------------------
__global__ __launch_bounds__(256) void h_kernel(const float* __restrict__ x,
                                                const float* __restrict__ theta,
                                                const float* __restrict__ W1,
                                                const float* __restrict__ b1,
                                                uint16_t* __restrict__ Hsw) {
  __shared__ float qs[64][8];
  int tid = threadIdx.x;
  long m0 = (long)blockIdx.x * 64;
  int g = blockIdx.y * 256 + tid;       // granule 0..511
  int f0 = g * 8;

  for (int idx = tid; idx < 512; idx += 256) {
    int t = idx >> 3, i = idx & 7;
    qs[t][i] = __cosf(theta[i]) * cosf(x[(m0 + t) * 1024 + i]);
  }
  __syncthreads();

  float4 w[16];
#pragma unroll
  for (int j = 0; j < 8; ++j) {
    w[2 * j]     = *(const float4*)(W1 + (long)(f0 + j) * 8);
    w[2 * j + 1] = *(const float4*)(W1 + (long)(f0 + j) * 8 + 4);
  }
  float bb[8];
#pragma unroll
  for (int j = 0; j < 8; ++j) bb[j] = b1[f0 + j];

  int blk = (g >> 3) * 64;
  int gw = g & 7;

#pragma unroll 2
  for (int t = 0; t < 64; ++t) {
    long m = m0 + t;
    float q0 = qs[t][0], q1 = qs[t][1], q2 = qs[t][2], q3 = qs[t][3];
    float q4 = qs[t][4], q5 = qs[t][5], q6 = qs[t][6], q7 = qs[t][7];
    union { uint16_t u[8]; uint4 v; } pk;
#pragma unroll
    for (int j = 0; j < 8; ++j) {
      float h = bb[j];
      h += q0 * w[2 * j].x + q1 * w[2 * j].y + q2 * w[2 * j].z + q3 * w[2 * j].w;
      h += q4 * w[2 * j + 1].x + q5 * w[2 * j + 1].y + q6 * w[2 * j + 1].z + q7 * w[2 * j + 1].w;
      h = fmaxf(h, 0.0f);
      pk.u[j] = f2bf(h);
    }
    int sg = gw ^ ((int)m & 7);
    *(uint4*)&Hsw[m * K_DIM + blk + sg * 8] = pk.v;
  }
}

// ---------------------------------------------------------------------------
// Kernel 3: 256x256 fully-rotated GEMM. out[m][n] = sum_k H[m][k]*W2[n][k]+b2
// 8 waves (2M x 4N), wave tile 128x64, acc[8][4] f32x4.
// LDS: A,B double-buffered [2][256][64] bf16 = 128 KiB.
// ---------------------------------------------------------------------------
__global__ __launch_bounds__(512, 2) void gemm_kernel(const uint16_t* __restrict__ Hsw,
                                                      const uint16_t* __restrict__ W2sw,
                                                      const float* __restrict__ b2,
                                                      float* __restrict__ out) {
  __shared__ uint16_t LA[2 * BM * BK];   // 64 KiB
  __shared__ uint16_t LB[2 * BN * BK];   // 64 KiB

  int nwg = gridDim.x;
  int bid = blockIdx.x;
  int sw = bid;
  if ((nwg & 7) == 0) { int cpx = nwg >> 3; sw = (bid & 7) * cpx + (bid >> 3); }
  const int NTN = N_DIM / BN;            // 4
  int mt = sw / NTN;
  int nt = sw - mt * NTN;
  long m0 = (long)mt * BM;
  int n0 = nt * BN;

  int tid = threadIdx.x;
  int lane = tid & 63;
  int wave_m = (tid >> 6) >> 2;          // 0..1
  int wave_n = (tid >> 6) & 3;           // 0..3
  int wmB = wave_m * 128;
  int wnB = wave_n * 64;

  int r  = lane & 15;
  int kq = lane >> 4;
  int xr = r & 7;

  int rowS = tid >> 3;
  int colS = (tid & 7) * 8;
  const uint16_t* srcA = Hsw  + (m0 + rowS) * K_DIM + colS;
  const uint16_t* srcB = W2sw + ((long)(n0 + rowS)) * K_DIM + colS;
  int ldsWB = (tid & ~63) * 8;

#define STAGE_A(p, h, j, t) \
  gload_lds16(srcA + (long)((h)*128 + (j)*64) * K_DIM + (t)*BK, \
              &LA[(p)*16384 + ((h)*128 + (j)*64)*BK + ldsWB])
#define STAGE_B(p, h, j, t) \
  gload_lds16(srcB + (long)((h)*128 + (j)*64) * K_DIM + (t)*BK, \
              &LB[(p)*16384 + ((h)*128 + (j)*64)*BK + ldsWB])

#define BAR() do { asm volatile("" ::: "memory"); __builtin_amdgcn_s_barrier(); \
                   asm volatile("" ::: "memory"); } while (0)

#define LDA_F(p, mf_, ks_) \
  (*(const short8*)&LA[(p)*16384 + (wmB + (mf_)*16 + r)*BK + ((((ks_)*4 + kq) ^ xr)*8)])
#define LDB_F(p, nf_, ks_) \
  (*(const short8*)&LB[(p)*16384 + (wnB + (nf_)*16 + r)*BK + ((((ks_)*4 + kq) ^ xr)*8)])

// quadrant MFMA: A-array (4 frags x 2 ks), B-array (2 frags x 2 ks)
#define MFMA_Q(AARR, BARR, mh, nh) do { \
    __builtin_amdgcn_s_setprio(1); \
    _Pragma("unroll") for (int i_ = 0; i_ < 4; ++i_) \
    _Pragma("unroll") for (int j_ = 0; j_ < 2; ++j_) \
    _Pragma("unroll") for (int ks_ = 0; ks_ < 2; ++ks_) \
      acc[(mh)*4 + i_][(nh)*2 + j_] = __builtin_amdgcn_mfma_f32_16x16x32_bf16( \
          AARR[i_][ks_], BARR[j_][ks_], acc[(mh)*4 + i_][(nh)*2 + j_], 0, 0, 0); \
    __builtin_amdgcn_s_setprio(0); \
  } while (0)

  f32x4 acc[8][4];
#pragma unroll
  for (int i = 0; i < 8; ++i)
#pragma unroll
    for (int j = 0; j < 4; ++j) acc[i][j] = (f32x4){0.f, 0.f, 0.f, 0.f};

  short8 a0[4][2];   // mh0 frags of current tile (read P3 of prev tile)
  short8 a1[4][2];   // mh1 frags of current tile (read P0)
  short8 b0[2][2];   // nh0 frags (read P3 of prev tile)
  short8 b1v[2][2];  // nh1 frags (read P0)

  // ---- prologue: tile0 -> buf0, tile1 -> buf1 (8 DMAs each)
#pragma unroll
  for (int h = 0; h < 2; ++h)
#pragma unroll
    for (int j = 0; j < 2; ++j) STAGE_A(0, h, j, 0);
#pragma unroll
  for (int h = 0; h < 2; ++h)
#pragma unroll
    for (int j = 0; j < 2; ++j) STAGE_B(0, h, j, 0);
#pragma unroll
  for (int h = 0; h < 2; ++h)
#pragma unroll
    for (int j = 0; j < 2; ++j) STAGE_A(1, h, j, 1);
#pragma unroll
  for (int h = 0; h < 2; ++h)
#pragma unroll
    for (int j = 0; j < 2; ++j) STAGE_B(1, h, j, 1);
  asm volatile("s_waitcnt vmcnt(8)" ::: "memory");   // own tile-0 DMAs landed
  BAR();                                             // block-wide landed
  // pre-read tile0's P0 operand set
#pragma unroll
  for (int i = 0; i < 4; ++i)
#pragma unroll
    for (int ks = 0; ks < 2; ++ks) a0[i][ks] = LDA_F(0, i, ks);
#pragma unroll
  for (int j = 0; j < 2; ++j)
#pragma unroll
    for (int ks = 0; ks < 2; ++ks) b0[j][ks] = LDB_F(0, j, ks);

#pragma unroll 2
  for (int u = 0; u < NT_K; ++u) {
    int p = u & 1;
    bool st = (u < NT_K - 2);
    bool rd = (u < NT_K - 1);

    // ---- P0: MFMA(0,0); read b1v (needed P1) + a1 (needed P2)
    MFMA_Q(a0, b0, 0, 0);
#pragma unroll
    for (int j = 0; j < 2; ++j)
#pragma unroll
      for (int ks = 0; ks < 2; ++ks) b1v[j][ks] = LDB_F(p, 2 + j, ks);
#pragma unroll
    for (int i = 0; i < 4; ++i)
#pragma unroll
      for (int ks = 0; ks < 2; ++ks) a1[i][ks] = LDA_F(p, 4 + i, ks);
    BAR();

    // ---- P1: MFMA(0,1); stage A-j0 of u+2 (consumed @P0, barrier'd)
    MFMA_Q(a0, b1v, 0, 1);
    if (st) { STAGE_A(p, 0, 0, u + 2); STAGE_A(p, 1, 0, u + 2); }
    BAR();

    // ---- P2: MFMA(1,1); stage all B of u+2 (consumed @P0/P1, barrier'd);
    //          counted vmcnt: drains tile u+1's 8 oldest DMAs.
    MFMA_Q(a1, b1v, 1, 1);
    if (st) { STAGE_B(p, 0, 0, u + 2); STAGE_B(p, 0, 1, u + 2);
              STAGE_B(p, 1, 0, u + 2); STAGE_B(p, 1, 1, u + 2); }
    if (st)                 { asm volatile("s_waitcnt vmcnt(6)" ::: "memory"); }
    else if (u == NT_K - 2) { asm volatile("s_waitcnt vmcnt(0)" ::: "memory"); }
    BAR();

    // ---- P3: MFMA(1,0); read next tile's a0/b0 from buffer p^1 (RAW-safe:
    //          every wave passed vmcnt @P2 + barrier); stage A-j1 of u+2.
    MFMA_Q(a1, b0, 1, 0);
    if (rd) {
#pragma unroll
      for (int i = 0; i < 4; ++i)
#pragma unroll
        for (int ks = 0; ks < 2; ++ks) a0[i][ks] = LDA_F(p ^ 1, i, ks);
#pragma unroll
      for (int j = 0; j < 2; ++j)
#pragma unroll
        for (int ks = 0; ks < 2; ++ks) b0[j][ks] = LDB_F(p ^ 1, j, ks);
    }
    if (st) { STAGE_A(p, 0, 1, u + 2); STAGE_A(p, 1, 1, u + 2); }
    BAR();
  }

  // ---- epilogue: C/D layout col = lane&15 (n), row = kq*4 + reg (m)
  float bb[4];
#pragma unroll
  for (int nf = 0; nf < 4; ++nf) bb[nf] = b2[n0 + wnB + nf * 16 + r];
  long mbase = m0 + wmB + kq * 4;
#pragma unroll
  for (int mf = 0; mf < 8; ++mf) {
#pragma unroll
    for (int nf = 0; nf < 4; ++nf) {
      int n = n0 + wnB + nf * 16 + r;
#pragma unroll
      for (int rg = 0; rg < 4; ++rg) {
        out[(mbase + mf * 16 + rg) * N_DIM + n] = acc[mf][nf][rg] + bb[nf];
      }
    }
  }
#undef STAGE_A
#undef STAGE_B
#undef BAR
#undef LDA_F
#undef LDB_F
#undef MFMA_Q
}

// ---------------------------------------------------------------------------
extern "C" void kernel_launch(void* const* d_in, const int* in_sizes, int n_in,
                              void* d_out, int out_size, void* d_ws, size_t ws_size,
                              hipStream_t stream) {
  const float* x     = (const float*)d_in[0];
  const float* theta = (const float*)d_in[1];
  const float* W1    = (const float*)d_in[2];
  const float* b1    = (const float*)d_in[3];
  const float* W2    = (const float*)d_in[4];
  const float* b2    = (const float*)d_in[5];
  float* out = (float*)d_out;

  const size_t W2SW_BYTES = (size_t)N_DIM * K_DIM * 2;   // 8 MiB
  uint16_t* W2sw = (uint16_t*)d_ws;
  uint16_t* Hsw  = (uint16_t*)((char*)d_ws + W2SW_BYTES);

  size_t avail = ws_size > W2SW_BYTES ? ws_size - W2SW_BYTES : 0;
  long CM = (long)(avail / ((size_t)K_DIM * 2));
  CM &= ~255L;                       // multiple of BM=256
  if (CM > CM_MAX) CM = CM_MAX;      // keep H-chunk (134 MB) L3-resident
  if (CM < 256) CM = 256;

  prep_w2<<<2048, 256, 0, stream>>>(W2, W2sw);

  for (long m0 = 0; m0 < M_TOT; m0 += CM) {
    long mc = M_TOT - m0;
    if (mc > CM) mc = CM;
    dim3 gA((unsigned)(mc / 64), 2);
    h_kernel<<<gA, 256, 0, stream>>>(x + m0 * N_DIM, theta, W1, b1, Hsw);
    unsigned ngb = (unsigned)((mc / BM) * (N_DIM / BN));
    gemm_kernel<<<ngb, 512, 0, stream>>>(Hsw, W2sw, b2, out + m0 * N_DIM);
  }
}